// Round 5
// baseline (123.055 us; speedup 1.0000x reference)
//
#include <hip/hip_runtime.h>

#define BB 4
#define TT 64
#define SS 256
#define DD 512
#define FEMB 128

typedef __attribute__((ext_vector_type(8))) short short8;    // 8 bf16 = 4 VGPRs
typedef __attribute__((ext_vector_type(4))) float floatx4;

__device__ __forceinline__ float fast_tanh(float x) {
    x = fminf(fmaxf(x, -10.f), 10.f);
    float t = __expf(2.f * x);
    return (t - 1.f) / (t + 1.f);
}

// 8 consecutive fp32, as raw register data (issued as two dwordx4 loads)
struct f8 { float4 lo, hi; };
__device__ __forceinline__ f8 ldf8(const float* p) {
    f8 r;
    r.lo = *(const float4*)p;
    r.hi = *(const float4*)(p + 4);
    return r;
}
__device__ __forceinline__ unsigned int fbits(float x) {
    union { float f; unsigned int u; } c; c.f = x; return c.u;
}
// truncate-pack 8 fp32 -> 8 bf16: one v_perm_b32 per pair
__device__ __forceinline__ short8 cvt8(f8 v) {
    union { unsigned int u[4]; short8 s; } r;
    r.u[0] = __builtin_amdgcn_perm(fbits(v.lo.y), fbits(v.lo.x), 0x07060302u);
    r.u[1] = __builtin_amdgcn_perm(fbits(v.lo.w), fbits(v.lo.z), 0x07060302u);
    r.u[2] = __builtin_amdgcn_perm(fbits(v.hi.y), fbits(v.hi.x), 0x07060302u);
    r.u[3] = __builtin_amdgcn_perm(fbits(v.hi.w), fbits(v.hi.z), 0x07060302u);
    return r.s;
}

// ---- bf16 MFMA GEMM+tanh with in-register fp32->bf16 conversion.
// C = tanh(A @ W^T + b).  A:[M,K], W:[512,K] row-major fp32.
// Packed 320 blocks of 64x64 tiles; 4 waves/block, wave = 16 rows x 64 cols
// (4x mfma_f32_16x16x32_bf16).  Fragments loaded straight from global
// (L2-resident), 1-iter register prefetch, no LDS, no barriers, no cvt pass.
__global__ __launch_bounds__(256) void gemm_mfma_kernel(
    const float* __restrict__ X, const float* __restrict__ Z, const float* __restrict__ Y,
    const float* __restrict__ W1, const float* __restrict__ b1,
    const float* __restrict__ W2, const float* __restrict__ b2,
    const float* __restrict__ W3, const float* __restrict__ b3,
    const float* __restrict__ W4, const float* __restrict__ b4,
    float* __restrict__ H, float* __restrict__ Fo,
    float* __restrict__ O2, float* __restrict__ O3)
{
    int id = blockIdx.x;
    const float* A; const float* W; const float* bias; float* C; int K;
    if (id < 128)      { A = X; W = W1; bias = b1; C = H;  K = 512; }
    else if (id < 256) { id -= 128; A = Z; W = W3; bias = b3; C = Fo; K = 128; }
    else if (id < 288) { id -= 256; A = Y; W = W2; bias = b2; C = O2; K = 512; }
    else               { id -= 288; A = Y; W = W4; bias = b4; C = O3; K = 512; }
    const int m0 = (id >> 3) * 64;
    const int n0 = (id & 7) * 64;
    const int wv   = threadIdx.x >> 6;   // wave 0..3 -> 16-row stripe
    const int lane = threadIdx.x & 63;
    const int fr   = lane & 15;          // fragment row (A) / col (B)
    const int kh   = (lane >> 4) * 8;    // k sub-offset

    const float* Ap = A + (m0 + wv * 16 + fr) * K + kh;
    const float* Wp = W + (n0 + fr) * K + kh;
    const int WS = 16 * K;               // n-tile stride in W

    floatx4 acc0 = {0.f,0.f,0.f,0.f}, acc1 = acc0, acc2 = acc0, acc3 = acc0;

    f8 ra  = ldf8(Ap);
    f8 rw0 = ldf8(Wp);
    f8 rw1 = ldf8(Wp + WS);
    f8 rw2 = ldf8(Wp + 2 * WS);
    f8 rw3 = ldf8(Wp + 3 * WS);

    for (int k0 = 0; k0 < K; k0 += 32) {
        const int kn = (k0 + 32 < K) ? (k0 + 32) : 0;  // wrap: dummy valid prefetch on last iter
        f8 na  = ldf8(Ap + kn);
        f8 nw0 = ldf8(Wp + kn);
        f8 nw1 = ldf8(Wp + WS + kn);
        f8 nw2 = ldf8(Wp + 2 * WS + kn);
        f8 nw3 = ldf8(Wp + 3 * WS + kn);
        short8 a  = cvt8(ra);            // depends on PREVIOUS iter's loads (complete)
        short8 w0 = cvt8(rw0);
        short8 w1 = cvt8(rw1);
        short8 w2 = cvt8(rw2);
        short8 w3 = cvt8(rw3);
        acc0 = __builtin_amdgcn_mfma_f32_16x16x32_bf16(a, w0, acc0, 0, 0, 0);
        acc1 = __builtin_amdgcn_mfma_f32_16x16x32_bf16(a, w1, acc1, 0, 0, 0);
        acc2 = __builtin_amdgcn_mfma_f32_16x16x32_bf16(a, w2, acc2, 0, 0, 0);
        acc3 = __builtin_amdgcn_mfma_f32_16x16x32_bf16(a, w3, acc3, 0, 0, 0);
        ra = na; rw0 = nw0; rw1 = nw1; rw2 = nw2; rw3 = nw3;
    }

    // C/D layout: col = lane&15, row = (lane>>4)*4 + reg   [m89-verified]
    const int orow  = m0 + wv * 16 + (lane >> 4) * 4;
    const int ocol0 = n0 + fr;
    const float bv0 = bias[ocol0], bv1 = bias[ocol0 + 16],
                bv2 = bias[ocol0 + 32], bv3 = bias[ocol0 + 48];
    #pragma unroll
    for (int r = 0; r < 4; ++r) {
        float* Cr = C + (orow + r) * DD + ocol0;
        Cr[0]  = fast_tanh(acc0[r] + bv0);
        Cr[16] = fast_tanh(acc1[r] + bv1);
        Cr[32] = fast_tanh(acc2[r] + bv2);
        Cr[48] = fast_tanh(acc3[r] + bv3);
    }
}

// ---- Attention: attn[b,t,d] = sum_s softmax_s(H*u + F*v) * enc.  |w|<=2, no max needed.
// 512 blocks x 512 threads: (b, t-pair, d-quarter) x 4-way in-block s-split.
__global__ __launch_bounds__(512) void attn_kernel(
    const float* __restrict__ H, const float* __restrict__ Fo,
    const float* __restrict__ X,   // enc, [1024,512] flat
    const float* __restrict__ O2, const float* __restrict__ O3,
    const float* __restrict__ Y,   // [256,512] flat
    float* __restrict__ out)
{
    const int idx = blockIdx.x;                    // 0..511
    const int b   = (idx & 7) >> 1;                // XCD-pair per batch
    const int rem = ((idx >> 3) << 1) | (idx & 1); // 0..127
    const int t0  = (rem >> 2) * 2;                // t-pair
    const int dq  = rem & 3;
    const int tid = threadIdx.x;
    const int dl  = tid & 127;
    const int d   = dq * 128 + dl;
    const int sq  = tid >> 7;                      // s-quarter 0..3

    const int bt0 = b * TT + t0;
    const float u0 = O2[bt0 * DD + d],       v0 = O3[bt0 * DD + d];
    const float u1 = O2[(bt0 + 1) * DD + d], v1 = O3[(bt0 + 1) * DD + d];

    float l0 = 0.f, l1 = 0.f, a0 = 0.f, a1 = 0.f;
    const int base = (b * SS + sq * 64) * DD + d;
    const float* Hb = H  + base;
    const float* Fb = Fo + base;
    const float* Eb = X  + base;

    for (int s0 = 0; s0 < 64; s0 += 8) {
        float h[8], f[8], e[8];
        #pragma unroll
        for (int s = 0; s < 8; ++s) h[s] = Hb[(s0 + s) * DD];
        #pragma unroll
        for (int s = 0; s < 8; ++s) f[s] = Fb[(s0 + s) * DD];
        #pragma unroll
        for (int s = 0; s < 8; ++s) e[s] = Eb[(s0 + s) * DD];
        #pragma unroll
        for (int s = 0; s < 8; ++s) {
            const float w0 = fmaf(h[s], u0, f[s] * v0);
            const float x0 = __expf(w0);
            l0 += x0; a0 = fmaf(x0, e[s], a0);
            const float w1 = fmaf(h[s], u1, f[s] * v1);
            const float x1 = __expf(w1);
            l1 += x1; a1 = fmaf(x1, e[s], a1);
        }
    }

    __shared__ float red[3][128][9];
    if (sq) {
        red[sq-1][dl][0] = l0; red[sq-1][dl][1] = l1;
        red[sq-1][dl][2] = a0; red[sq-1][dl][3] = a1;
    }
    __syncthreads();
    if (sq == 0) {
        #pragma unroll
        for (int q = 0; q < 3; ++q) {
            l0 += red[q][dl][0]; l1 += red[q][dl][1];
            a0 += red[q][dl][2]; a1 += red[q][dl][3];
        }
        const float r0 = a0 / l0, r1 = a1 / l1;
        out[BB * TT * 2 * DD + bt0 * DD + d]       = r0;
        out[BB * TT * 2 * DD + (bt0 + 1) * DD + d] = r1;
        out[bt0 * 2 * DD + DD + d]                 = r0;
        out[(bt0 + 1) * 2 * DD + DD + d]           = r1;
        out[bt0 * 2 * DD + d]                      = Y[bt0 * DD + d];
        out[(bt0 + 1) * 2 * DD + d]                = Y[(bt0 + 1) * DD + d];
    }
}

extern "C" void kernel_launch(void* const* d_in, const int* in_sizes, int n_in,
                              void* d_out, int out_size, void* d_ws, size_t ws_size,
                              hipStream_t stream)
{
    const float* Y  = (const float*)d_in[0];   // output          [4,64,512]
    const float* X  = (const float*)d_in[1];   // encoder_hidden  [1024,512] flat
    const float* Z  = (const float*)d_in[2];   // input_z         [1024,128] flat
    const float* W1 = (const float*)d_in[3];
    const float* b1 = (const float*)d_in[4];
    const float* W2 = (const float*)d_in[5];
    const float* b2 = (const float*)d_in[6];
    const float* W3 = (const float*)d_in[7];
    const float* b3 = (const float*)d_in[8];
    const float* W4 = (const float*)d_in[9];
    const float* b4 = (const float*)d_in[10];
    float* out = (float*)d_out;

    float* H  = (float*)d_ws;            // [1024,512] fp32
    float* Fo = H  + 1024 * 512;         // [1024,512] fp32
    float* O2 = Fo + 1024 * 512;         // [256,512]  fp32
    float* O3 = O2 + 256 * 512;          // [256,512]  fp32

    gemm_mfma_kernel<<<320, 256, 0, stream>>>(X, Z, Y, W1, b1, W2, b2, W3, b3, W4, b4,
                                              H, Fo, O2, O3);
    attn_kernel<<<512, 512, 0, stream>>>(H, Fo, X, O2, O3, Y, out);
}

// Round 6
// 115.511 us; speedup vs baseline: 1.0653x; 1.0653x over previous
//
#include <hip/hip_runtime.h>

#define BB 4
#define TT 64
#define SS 256
#define DD 512
#define FEMB 128

typedef __attribute__((ext_vector_type(8))) short short8;    // 8 bf16 = 4 VGPRs
typedef __attribute__((ext_vector_type(4))) float floatx4;

__device__ __forceinline__ float fast_tanh(float x) {
    x = fminf(fmaxf(x, -10.f), 10.f);
    float t = __expf(2.f * x);
    return (t - 1.f) / (t + 1.f);
}

// RNE-pack two fp32 into a uint of two bf16 (lo, hi)
__device__ __forceinline__ unsigned int pack_bf2(float a, float b) {
    union { float f; unsigned int u; } ca, cb;
    ca.f = a; cb.f = b;
    unsigned int ua = ca.u + 0x7FFF + ((ca.u >> 16) & 1);
    unsigned int ub = cb.u + 0x7FFF + ((cb.u >> 16) & 1);
    return (ua >> 16) | (ub & 0xFFFF0000u);
}

// ---- fp32 -> bf16 pre-convert: X, Z, Y, W1, W2, W3, W4 (1.64M elems)
__global__ __launch_bounds__(256) void cvt_kernel(
    const float* __restrict__ X, const float* __restrict__ Z, const float* __restrict__ Y,
    const float* __restrict__ W1, const float* __restrict__ W2,
    const float* __restrict__ W3, const float* __restrict__ W4,
    unsigned short* __restrict__ Xb, unsigned short* __restrict__ Zb,
    unsigned short* __restrict__ Yb, unsigned short* __restrict__ W1b,
    unsigned short* __restrict__ W2b, unsigned short* __restrict__ W3b,
    unsigned short* __restrict__ W4b)
{
    const int e = (blockIdx.x * 256 + threadIdx.x) * 4;
    const float* src; unsigned short* dst; int off;
    if (e < 524288)       { src = X;  dst = Xb;  off = 0; }
    else if (e < 655360)  { src = Z;  dst = Zb;  off = 524288; }
    else if (e < 786432)  { src = Y;  dst = Yb;  off = 655360; }
    else if (e < 1048576) { src = W1; dst = W1b; off = 786432; }
    else if (e < 1310720) { src = W2; dst = W2b; off = 1048576; }
    else if (e < 1376256) { src = W3; dst = W3b; off = 1310720; }
    else                  { src = W4; dst = W4b; off = 1376256; }
    const int i = e - off;
    float4 v = *(const float4*)&src[i];
    uint2 p;
    p.x = pack_bf2(v.x, v.y);
    p.y = pack_bf2(v.z, v.w);
    *(uint2*)&dst[i] = p;
}

// ---- bf16 MFMA GEMM+tanh: C = tanh(A @ W^T + b).  A:[M,K], W:[512,K] row-major bf16.
// Packed 320 blocks of 64x64 tiles; 4 waves/block, wave = 16 rows x 64 cols
// (4x mfma_f32_16x16x32_bf16).  Fragments loaded straight from global (L2-resident),
// 1-iter register prefetch, no LDS, no barriers.   [R4-proven]
__global__ __launch_bounds__(256) void gemm_mfma_kernel(
    const unsigned short* __restrict__ Xb, const unsigned short* __restrict__ Zb,
    const unsigned short* __restrict__ Yb,
    const unsigned short* __restrict__ W1b, const unsigned short* __restrict__ W2b,
    const unsigned short* __restrict__ W3b, const unsigned short* __restrict__ W4b,
    const float* __restrict__ b1, const float* __restrict__ b2,
    const float* __restrict__ b3, const float* __restrict__ b4,
    float* __restrict__ H, float* __restrict__ Fo,
    float* __restrict__ O2, float* __restrict__ O3)
{
    int id = blockIdx.x;
    const unsigned short* A; const unsigned short* W; const float* bias; float* C; int K;
    if (id < 128)      { A = Xb; W = W1b; bias = b1; C = H;  K = 512; }
    else if (id < 256) { id -= 128; A = Zb; W = W3b; bias = b3; C = Fo; K = 128; }
    else if (id < 288) { id -= 256; A = Yb; W = W2b; bias = b2; C = O2; K = 512; }
    else               { id -= 288; A = Yb; W = W4b; bias = b4; C = O3; K = 512; }
    const int m0 = (id >> 3) * 64;
    const int n0 = (id & 7) * 64;
    const int wv   = threadIdx.x >> 6;   // wave 0..3 -> 16-row stripe
    const int lane = threadIdx.x & 63;
    const int fr   = lane & 15;          // fragment row (A) / col (B)
    const int kh   = (lane >> 4) * 8;    // k sub-offset

    const unsigned short* Ap = A + (m0 + wv * 16 + fr) * K + kh;
    const unsigned short* Wp = W + (n0 + fr) * K + kh;
    const int WS = 16 * K;               // n-tile stride in W

    floatx4 acc0 = {0.f,0.f,0.f,0.f}, acc1 = acc0, acc2 = acc0, acc3 = acc0;

    short8 a  = *(const short8*)Ap;
    short8 w0 = *(const short8*)(Wp);
    short8 w1 = *(const short8*)(Wp + WS);
    short8 w2 = *(const short8*)(Wp + 2 * WS);
    short8 w3 = *(const short8*)(Wp + 3 * WS);

    for (int k0 = 0; k0 < K; k0 += 32) {
        const int kn = (k0 + 32 < K) ? (k0 + 32) : 0;   // wrap: dummy valid prefetch on last iter
        short8 an  = *(const short8*)(Ap + kn);
        short8 wn0 = *(const short8*)(Wp + kn);
        short8 wn1 = *(const short8*)(Wp + WS + kn);
        short8 wn2 = *(const short8*)(Wp + 2 * WS + kn);
        short8 wn3 = *(const short8*)(Wp + 3 * WS + kn);
        acc0 = __builtin_amdgcn_mfma_f32_16x16x32_bf16(a, w0, acc0, 0, 0, 0);
        acc1 = __builtin_amdgcn_mfma_f32_16x16x32_bf16(a, w1, acc1, 0, 0, 0);
        acc2 = __builtin_amdgcn_mfma_f32_16x16x32_bf16(a, w2, acc2, 0, 0, 0);
        acc3 = __builtin_amdgcn_mfma_f32_16x16x32_bf16(a, w3, acc3, 0, 0, 0);
        a = an; w0 = wn0; w1 = wn1; w2 = wn2; w3 = wn3;
    }

    // C/D layout: col = lane&15, row = (lane>>4)*4 + reg   [m89-verified]
    const int orow  = m0 + wv * 16 + (lane >> 4) * 4;
    const int ocol0 = n0 + fr;
    const float bv0 = bias[ocol0], bv1 = bias[ocol0 + 16],
                bv2 = bias[ocol0 + 32], bv3 = bias[ocol0 + 48];
    #pragma unroll
    for (int r = 0; r < 4; ++r) {
        float* Cr = C + (orow + r) * DD + ocol0;
        Cr[0]  = fast_tanh(acc0[r] + bv0);
        Cr[16] = fast_tanh(acc1[r] + bv1);
        Cr[32] = fast_tanh(acc2[r] + bv2);
        Cr[48] = fast_tanh(acc3[r] + bv3);
    }
}

// ---- Attention: attn[b,t,d] = sum_s softmax_s(H*u + F*v) * enc.  |w|<=2, no max needed.
// 1024 blocks x 512 threads: (b, t, d-quarter) x 4-way in-block s-split.
// 8192 waves = 32 waves/CU (occupancy cap); 8-deep load batches for ILP.
__global__ __launch_bounds__(512) void attn_kernel(
    const float* __restrict__ H, const float* __restrict__ Fo,
    const float* __restrict__ X,   // enc, [1024,512] flat
    const float* __restrict__ O2, const float* __restrict__ O3,
    const float* __restrict__ Y,   // [256,512] flat
    float* __restrict__ out)
{
    const int idx = blockIdx.x;                    // 0..1023
    const int b   = (idx & 7) >> 1;                // XCD-pair per batch
    const int rem = ((idx >> 3) << 1) | (idx & 1); // 0..255
    const int t   = rem >> 2;                      // 0..63
    const int dq  = rem & 3;
    const int tid = threadIdx.x;
    const int dl  = tid & 127;
    const int d   = dq * 128 + dl;
    const int sq  = tid >> 7;                      // s-quarter 0..3

    const int bt = b * TT + t;
    const float u = O2[bt * DD + d], v = O3[bt * DD + d];

    float l = 0.f, a = 0.f;
    const int base = (b * SS + sq * 64) * DD + d;
    const float* Hb = H  + base;
    const float* Fb = Fo + base;
    const float* Eb = X  + base;

    for (int s0 = 0; s0 < 64; s0 += 8) {
        float h[8], f[8], e[8];
        #pragma unroll
        for (int s = 0; s < 8; ++s) h[s] = Hb[(s0 + s) * DD];
        #pragma unroll
        for (int s = 0; s < 8; ++s) f[s] = Fb[(s0 + s) * DD];
        #pragma unroll
        for (int s = 0; s < 8; ++s) e[s] = Eb[(s0 + s) * DD];
        #pragma unroll
        for (int s = 0; s < 8; ++s) {
            const float w = fmaf(h[s], u, f[s] * v);
            const float x = __expf(w);
            l += x; a = fmaf(x, e[s], a);
        }
    }

    __shared__ float red[3][128][5];   // stride 5: coprime with 32 banks -> <=2-way (free)
    if (sq) { red[sq-1][dl][0] = l; red[sq-1][dl][1] = a; }
    __syncthreads();
    if (sq == 0) {
        #pragma unroll
        for (int q = 0; q < 3; ++q) { l += red[q][dl][0]; a += red[q][dl][1]; }
        const float r = a / l;
        out[BB * TT * 2 * DD + bt * DD + d] = r;               // attn (output 1)
        out[bt * 2 * DD + DD + d]           = r;               // concat second half
        out[bt * 2 * DD + d]                = Y[bt * DD + d];  // concat first half
    }
}

extern "C" void kernel_launch(void* const* d_in, const int* in_sizes, int n_in,
                              void* d_out, int out_size, void* d_ws, size_t ws_size,
                              hipStream_t stream)
{
    const float* Y  = (const float*)d_in[0];   // output          [4,64,512]
    const float* X  = (const float*)d_in[1];   // encoder_hidden  [1024,512] flat
    const float* Z  = (const float*)d_in[2];   // input_z         [1024,128] flat
    const float* W1 = (const float*)d_in[3];
    const float* b1 = (const float*)d_in[4];
    const float* W2 = (const float*)d_in[5];
    const float* b2 = (const float*)d_in[6];
    const float* W3 = (const float*)d_in[7];
    const float* b3 = (const float*)d_in[8];
    const float* W4 = (const float*)d_in[9];
    const float* b4 = (const float*)d_in[10];
    float* out = (float*)d_out;

    float* H  = (float*)d_ws;            // [1024,512] fp32
    float* Fo = H  + 1024 * 512;         // [1024,512] fp32
    float* O2 = Fo + 1024 * 512;         // [256,512]  fp32
    float* O3 = O2 + 256 * 512;          // [256,512]  fp32
    unsigned short* Xb  = (unsigned short*)(O3 + 256 * 512);  // bf16 region (16B-aligned)
    unsigned short* Zb  = Xb  + 524288;
    unsigned short* Yb  = Zb  + 131072;
    unsigned short* W1b = Yb  + 131072;
    unsigned short* W2b = W1b + 262144;
    unsigned short* W3b = W2b + 262144;
    unsigned short* W4b = W3b + 65536;

    cvt_kernel<<<1600, 256, 0, stream>>>(X, Z, Y, W1, W2, W3, W4,
                                         Xb, Zb, Yb, W1b, W2b, W3b, W4b);
    gemm_mfma_kernel<<<320, 256, 0, stream>>>(Xb, Zb, Yb, W1b, W2b, W3b, W4b,
                                              b1, b2, b3, b4, H, Fo, O2, O3);
    attn_kernel<<<1024, 512, 0, stream>>>(H, Fo, X, O2, O3, Y, out);
}